// Round 8
// baseline (199.235 us; speedup 1.0000x reference)
//
#include <hip/hip_runtime.h>

// out[b,o,n] = sum_{i,k} x[b,i,4n+k] * w[o,i,4n+k] / sqrt(128)
// Round-8: two-pass, pack rebuilt as LDS-transpose.
//   r7 evidence: gemm2 on packed data ~42us (5.6 TB/s). pack was 156us:
//   64B writes at 512KB stride = partial 128B L2 lines -> DRAM RMW ~3x amp.
//   New pack: contiguous 1KB/instr reads, LDS transpose, >=512B contiguous
//   full-line writes. Layouts (unchanged, gemm2-verified):
//     Xp[ng 128][i 128][b 64][nk 32]   (64 MB bf16)
//     Wp[ng*2+oh][i 128][o' 64][nk 32] (128 MB bf16)

#define CIN  128
#define COUT 128
#define ODIM 1024
#define DDIM 4096
#define NGS   128
#define NGSTR 262144
#define XP_SHORTS (NGS * NGSTR)
#define WP_SHORTS (2 * NGS * NGSTR)
#define WS_NEED   ((size_t)(XP_SHORTS + WP_SHORTS) * 2)

typedef short bf16x8 __attribute__((ext_vector_type(8)));
typedef short s16x8  __attribute__((ext_vector_type(8)));
typedef short s16x4  __attribute__((ext_vector_type(4)));
typedef float f32x4  __attribute__((ext_vector_type(4)));

static __device__ __forceinline__ unsigned short f2bf(float f) {
    unsigned int u = __float_as_uint(f);
    u += 0x7fffu + ((u >> 16) & 1u);   // RNE fp32 -> bf16
    return (unsigned short)(u >> 16);
}
static __device__ __forceinline__ s16x4 cvt4(float4 v) {
    s16x4 s;
    s[0] = (short)f2bf(v.x); s[1] = (short)f2bf(v.y);
    s[2] = (short)f2bf(v.z); s[3] = (short)f2bf(v.w);
    return s;
}

#define GLD(dst, off, base) \
    asm volatile("global_load_dwordx4 %0, %1, %2" : "=v"(dst) : "v"(off), "s"(base))

// ---------------- Pass 1: LDS-transpose pack ----------------
// Block = 32 rows (fixed i; b-half for x, o-quarter for w). 8 phases of a
// 512-float d-window: read 32x2KB contiguous -> LDS (swizzled) -> write
// 16 ngs x 2KB contiguous chunks (full L2 lines, no RMW).
__global__ __launch_bounds__(512, 4)
void pack2_kernel(const float* __restrict__ xg, const float* __restrict__ wg,
                  short* __restrict__ Xp, short* __restrict__ Wp) {
    __shared__ short lds[16384];   // [row 32][slot 128][4 shorts] = 32 KB

    const int bid = blockIdx.x;
    const float* srcBase;
    short* dstBase;
    unsigned ngmul;
    if (bid < 256) {                       // x: i = bid>>1, b-half = bid&1
        const int i = bid >> 1, bh = bid & 1;
        srcBase = xg + ((size_t)(bh * 32) * CIN + i) * DDIM;
        dstBase = Xp + i * 2048 + bh * 1024;
        ngmul = NGSTR;
    } else {                               // w: i, o-half, o-quarter-in-half
        const int q = bid - 256;
        const int i = q >> 2, oh = (q >> 1) & 1, o1 = q & 1;
        srcBase = wg + ((size_t)(oh * 64 + o1 * 32) * CIN + i) * DDIM;
        dstBase = Wp + (size_t)oh * NGSTR + i * 2048 + o1 * 1024;
        ngmul = 2u * NGSTR;
    }

    const int t  = threadIdx.x;
    const int f4 = t & 127;        // float4 index within the 512-float window
    const int rl = t >> 7;         // row low bits (row = 4j + rl)
    const int ngloc = t >> 5;      // out-phase: ng within window (0..15)
    const int s5    = t & 31;

    float4 g0, g1, g2, g3, g4, g5, g6, g7;
    const unsigned vb = (unsigned)rl * 2097152u + (unsigned)f4 * 16u;

#define PISSUE(p) do { unsigned _o = vb + (unsigned)(p) * 2048u;             \
    GLD(g0, _o,             srcBase); GLD(g1, _o +  8388608u, srcBase);      \
    GLD(g2, _o + 16777216u, srcBase); GLD(g3, _o + 25165824u, srcBase);      \
    GLD(g4, _o + 33554432u, srcBase); GLD(g5, _o + 41943040u, srcBase);      \
    GLD(g6, _o + 50331648u, srcBase); GLD(g7, _o + 58720256u, srcBase); } while (0)

#define PDSW(g, j) do { const int _row = 4 * (j) + rl;                       \
    *reinterpret_cast<s16x4*>(                                               \
        &lds[_row * 512 + ((f4 ^ (_row & 7)) << 2)]) = cvt4(g); } while (0)

    PISSUE(0);
#pragma unroll 1
    for (int p = 0; p < 8; ++p) {
        if (p == 0) { asm volatile("s_waitcnt vmcnt(0)" ::: "memory"); }
        else        { asm volatile("s_waitcnt vmcnt(4)" ::: "memory"); }  // 8 loads retired (VM in-order; 4 stores younger)
        __builtin_amdgcn_sched_barrier(0);
        PDSW(g0, 0); PDSW(g1, 1); PDSW(g2, 2); PDSW(g3, 3);
        PDSW(g4, 4); PDSW(g5, 5); PDSW(g6, 6); PDSW(g7, 7);
        if (p < 7) PISSUE(p + 1);           // in flight across the out-phase
        asm volatile("s_waitcnt lgkmcnt(0)" ::: "memory");
        __builtin_amdgcn_sched_barrier(0);
        __builtin_amdgcn_s_barrier();

        // out-phase: 16 ngs x [row 32][nk 32] = 2 KB contiguous each
        short* dp = dstBase + (size_t)(p * 16 + ngloc) * ngmul;
#pragma unroll
        for (int v = 0; v < 4; ++v) {
            const int unit = s5 + 32 * v;        // 16B unit within 2KB chunk
            const int row = unit >> 2, nkq = unit & 3;
            const int f4a = ngloc * 8 + nkq * 2;
            const int r7b = row & 7;
            s16x4 va = *reinterpret_cast<const s16x4*>(
                &lds[row * 512 + ((f4a ^ r7b) << 2)]);
            s16x4 vb2 = *reinterpret_cast<const s16x4*>(
                &lds[row * 512 + (((f4a + 1) ^ r7b) << 2)]);
            *reinterpret_cast<s16x8*>(dp + unit * 8) =
                __builtin_shufflevector(va, vb2, 0, 1, 2, 3, 4, 5, 6, 7);
        }
        __builtin_amdgcn_s_barrier();           // LDS reuse guard
    }
#undef PISSUE
#undef PDSW
}

// ---------------- Pass 2: GEMM on packed layout (verbatim r7, validated) ----------------
__global__ __launch_bounds__(512, 4)
void gemm2_kernel(const short* __restrict__ Xp, const short* __restrict__ Wp,
                  float* __restrict__ outg) {
    __shared__ short xs[64 * 256];   // 32 KB
    __shared__ short ws2[64 * 256];  // 32 KB

    const int bid  = blockIdx.x;
    const int gidx = (bid & 7) * 32 + (bid >> 3);   // XCD-contiguous
    const int ng   = gidx >> 1;                      // 0..127
    const int oh   = gidx & 1;

    const int t    = threadIdx.x;
    const int lane = t & 63;
    const int wave = t >> 6;
    const int bt   = wave & 3;
    const int ot   = wave >> 2;
    const int r16  = lane & 15;
    const int kg   = lane >> 4;

    const short* xb = Xp + (size_t)ng * NGSTR;
    const short* wb = Wp + (size_t)(ng * 2 + oh) * NGSTR;

    const int srow = (t >> 2) & 63;
    const int sn0  = (t & 3) * 2;
    const int sib  = t >> 8;
    const int sb7  = srow & 7;
    const int ss0  = sn0 ^ sb7;
    const unsigned tb = (unsigned)t * 16u;

    f32x4 acc[2][8];
#pragma unroll
    for (int j = 0; j < 2; ++j)
#pragma unroll
        for (int n = 0; n < 8; ++n) acc[j][n] = (f32x4){0.f, 0.f, 0.f, 0.f};

    s16x8 px0, px1, px2, px3, pw0, pw1, pw2, pw3;

#define ISSUE_X(c) do { unsigned _o = tb + (unsigned)(c) * 32768u;           \
    GLD(px0, _o, xb); GLD(px1, _o + 8192u, xb);                              \
    GLD(px2, _o + 16384u, xb); GLD(px3, _o + 24576u, xb); } while (0)
#define ISSUE_W(c) do { unsigned _o = tb + (unsigned)(c) * 32768u;           \
    GLD(pw0, _o, wb); GLD(pw1, _o + 8192u, wb);                              \
    GLD(pw2, _o + 16384u, wb); GLD(pw3, _o + 24576u, wb); } while (0)

#define ST1(arr, v, it) do {                                                 \
    const int _a = srow * 256 + ((it) * 2 + sib) * 32 + ss0 * 4;             \
    const int _b = srow * 256 + ((it) * 2 + sib) * 32 + (ss0 ^ 1) * 4;       \
    *reinterpret_cast<s16x4*>(&arr[_a]) =                                    \
        __builtin_shufflevector(v, v, 0, 1, 2, 3);                           \
    *reinterpret_cast<s16x4*>(&arr[_b]) =                                    \
        __builtin_shufflevector(v, v, 4, 5, 6, 7);                           \
    } while (0)
#define STX() do { ST1(xs, px0, 0); ST1(xs, px1, 1); ST1(xs, px2, 2); ST1(xs, px3, 3); } while (0)
#define STW() do { ST1(ws2, pw0, 0); ST1(ws2, pw1, 1); ST1(ws2, pw2, 2); ST1(ws2, pw3, 3); } while (0)

#define VMW4() do { asm volatile("s_waitcnt vmcnt(4)" ::: "memory");         \
                    __builtin_amdgcn_sched_barrier(0); } while (0)
#define VMW0() do { asm volatile("s_waitcnt vmcnt(0)" ::: "memory");         \
                    __builtin_amdgcn_sched_barrier(0); } while (0)

    const int xrow  = (bt * 16 + r16) * 256;
    const int orow0 = (ot * 32 + r16) * 256;
    const int orow1 = (ot * 32 + 16 + r16) * 256;
    const int rb7   = r16 & 7;
    const int kgo   = kg * 64;

    ISSUE_X(0); ISSUE_W(0);
#pragma unroll 1
    for (int c = 0; c < 16; ++c) {
        VMW4();
        STX();
        if (c + 1 < 16) ISSUE_X(c + 1);
        if (c + 1 < 16) { VMW4(); }
        else            { VMW0(); }
        STW();
        if (c + 1 < 16) ISSUE_W(c + 1);
        asm volatile("s_waitcnt lgkmcnt(0)" ::: "memory");
        __builtin_amdgcn_sched_barrier(0);
        __builtin_amdgcn_s_barrier();

#pragma unroll
        for (int n = 0; n < 8; ++n) {
            const int so = (n ^ rb7) * 4;
            s16x4 a0 = *reinterpret_cast<const s16x4*>(&xs[xrow + kgo + so]);
            s16x4 a1 = *reinterpret_cast<const s16x4*>(&xs[xrow + kgo + 32 + so]);
            s16x4 b0 = *reinterpret_cast<const s16x4*>(&ws2[orow0 + kgo + so]);
            s16x4 b1 = *reinterpret_cast<const s16x4*>(&ws2[orow0 + kgo + 32 + so]);
            s16x4 c0 = *reinterpret_cast<const s16x4*>(&ws2[orow1 + kgo + so]);
            s16x4 c1 = *reinterpret_cast<const s16x4*>(&ws2[orow1 + kgo + 32 + so]);
            bf16x8 A  = __builtin_shufflevector(a0, a1, 0, 1, 2, 3, 4, 5, 6, 7);
            bf16x8 B0 = __builtin_shufflevector(b0, b1, 0, 1, 2, 3, 4, 5, 6, 7);
            bf16x8 B1 = __builtin_shufflevector(c0, c1, 0, 1, 2, 3, 4, 5, 6, 7);
            acc[0][n] = __builtin_amdgcn_mfma_f32_16x16x32_bf16(A, B0, acc[0][n], 0, 0, 0);
            acc[1][n] = __builtin_amdgcn_mfma_f32_16x16x32_bf16(A, B1, acc[1][n], 0, 0, 0);
        }
        if (c + 1 < 16) __builtin_amdgcn_s_barrier();
    }

    const float scale = 0.08838834764831845f;  // 1/sqrt(128)
#pragma unroll
    for (int osub = 0; osub < 2; ++osub) {
        const int o = oh * 64 + ot * 32 + osub * 16 + r16;
#pragma unroll
        for (int r = 0; r < 4; ++r) {
            const int b = bt * 16 + kg * 4 + r;
            float* op = outg + ((size_t)b * COUT + o) * ODIM + ng * 8;
            float4 v0, v1;
            v0.x = acc[osub][0][r] * scale; v0.y = acc[osub][1][r] * scale;
            v0.z = acc[osub][2][r] * scale; v0.w = acc[osub][3][r] * scale;
            v1.x = acc[osub][4][r] * scale; v1.y = acc[osub][5][r] * scale;
            v1.z = acc[osub][6][r] * scale; v1.w = acc[osub][7][r] * scale;
            *reinterpret_cast<float4*>(op)     = v0;
            *reinterpret_cast<float4*>(op + 4) = v1;
        }
    }
}

// ---------------- Fallback (r6-style single pass) if ws too small ----------------
#define RS 512
__global__ __launch_bounds__(512, 4)
void nolc_fallback(const float* __restrict__ xg, const float* __restrict__ wg,
                   float* __restrict__ outg) {
    __shared__ short lds[64 * RS];
    const int bid  = blockIdx.x;
    const int gidx = (bid & 7) * 64 + (bid >> 3);
    const int ng   = gidx >> 3;
    const int bq   = (gidx >> 2) & 1;
    const int oq   = gidx & 3;
    const int t = threadIdx.x, lane = t & 63, wave = t >> 6;
    const int sn = t & 15, si = (t >> 4) & 7, rl = t >> 7;
    const float* px = xg + ((size_t)(bq * 32 + rl) * CIN + si) * DDIM + ng * 64 + sn * 4;
    const float* pw = wg + ((size_t)(oq * 32 + rl) * CIN + si) * DDIM + ng * 64 + sn * 4;
    const size_t R4 = (size_t)4 * CIN * DDIM, CH = (size_t)8 * DDIM;
    const int bt = wave & 1, ot = (wave >> 1) & 1, nh = wave >> 2;
    const int r16 = lane & 15, kg = lane >> 4;
    f32x4 acc[8];
#pragma unroll
    for (int n = 0; n < 8; ++n) acc[n] = (f32x4){0.f, 0.f, 0.f, 0.f};
    const int xbase = (bt * 16 + r16) * RS, wbase = (32 + ot * 16 + r16) * RS;
#pragma unroll 1
    for (int c = 0; c < 16; ++c) {
        float4 rx[8], rw[8];
#pragma unroll
        for (int it = 0; it < 8; ++it) {
            rx[it] = *reinterpret_cast<const float4*>(px + c * CH + it * R4);
            rw[it] = *reinterpret_cast<const float4*>(pw + c * CH + it * R4);
        }
#pragma unroll
        for (int it = 0; it < 8; ++it) {
            const int row = it * 4 + rl;
            *reinterpret_cast<s16x4*>(&lds[row * RS + si * 64 + ((sn ^ (row & 15)) << 2)]) = cvt4(rx[it]);
            const int row2 = 32 + it * 4 + rl;
            *reinterpret_cast<s16x4*>(&lds[row2 * RS + si * 64 + ((sn ^ (row2 & 15)) << 2)]) = cvt4(rw[it]);
        }
        __syncthreads();
#pragma unroll
        for (int nn = 0; nn < 8; ++nn) {
            const int n = nh * 8 + nn, so = (n ^ r16) << 2;
            s16x4 a0 = *reinterpret_cast<const s16x4*>(&lds[xbase + (kg * 2) * 64 + so]);
            s16x4 a1 = *reinterpret_cast<const s16x4*>(&lds[xbase + (kg * 2 + 1) * 64 + so]);
            s16x4 b0 = *reinterpret_cast<const s16x4*>(&lds[wbase + (kg * 2) * 64 + so]);
            s16x4 b1 = *reinterpret_cast<const s16x4*>(&lds[wbase + (kg * 2 + 1) * 64 + so]);
            bf16x8 A = __builtin_shufflevector(a0, a1, 0, 1, 2, 3, 4, 5, 6, 7);
            bf16x8 B = __builtin_shufflevector(b0, b1, 0, 1, 2, 3, 4, 5, 6, 7);
            acc[nn] = __builtin_amdgcn_mfma_f32_16x16x32_bf16(A, B, acc[nn], 0, 0, 0);
        }
        if (c + 1 < 16) __syncthreads();
    }
    const float scale = 0.08838834764831845f;
    const int o = oq * 32 + ot * 16 + r16;
#pragma unroll
    for (int r = 0; r < 4; ++r) {
        const int b = bq * 32 + bt * 16 + kg * 4 + r;
        float* op = outg + ((size_t)b * COUT + o) * ODIM + ng * 16 + nh * 8;
        float4 v0, v1;
        v0.x = acc[0][r] * scale; v0.y = acc[1][r] * scale;
        v0.z = acc[2][r] * scale; v0.w = acc[3][r] * scale;
        v1.x = acc[4][r] * scale; v1.y = acc[5][r] * scale;
        v1.z = acc[6][r] * scale; v1.w = acc[7][r] * scale;
        *reinterpret_cast<float4*>(op) = v0;
        *reinterpret_cast<float4*>(op + 4) = v1;
    }
}

extern "C" void kernel_launch(void* const* d_in, const int* in_sizes, int n_in,
                              void* d_out, int out_size, void* d_ws, size_t ws_size,
                              hipStream_t stream) {
    const float* x = (const float*)d_in[0];
    const float* w = (const float*)d_in[1];
    float* out = (float*)d_out;
    if (ws_size >= WS_NEED) {
        short* Xp = (short*)d_ws;
        short* Wp = Xp + XP_SHORTS;
        pack2_kernel<<<dim3(768), dim3(512), 0, stream>>>(x, w, Xp, Wp);
        gemm2_kernel<<<dim3(256), dim3(512), 0, stream>>>(Xp, Wp, out);
    } else {
        nolc_fallback<<<dim3(512), dim3(512), 0, stream>>>(x, w, out);
    }
}

// Round 9
// 166.635 us; speedup vs baseline: 1.1956x; 1.1956x over previous
//
#include <hip/hip_runtime.h>

// out[b,o,n] = sum_{i,k} x[b,i,4n+k] * w[o,i,4n+k] / sqrt(128)
// x: (64,128,4096) f32, w: (128,128,4096) f32, out: (64,128,1024) f32.
//
// Round-9: test the DMA path. Evidence r1-r8: every kernel reading the fp32
// inputs via vector loads caps at ~2.4-2.9 TB/s read regardless of pattern/
// conflicts/occupancy (TCP miss-queue x latency bound); L3-sourced reads ran
// 2x faster (gemm2). global_load_lds is the one untested load mechanism —
// if its miss queue is deeper than TCP's, the wall breaks.
// Structure: block 64b x 64o x 4n, 1024 thr. fp32 staged via global_load_lds
// (width 16) into a 3-slot x 32KB ring, counted vmcnt(4) never drains.
// Each wave reads back only ITS OWN linear region (conflict-free, no
// cross-wave dependency), cvt_pk to bf16, rewrite into 32KB XOR-swizzled
// tile (write & MFMA-read both ~2-way = free). 3 barriers/chunk. LDS 128KB.

#define CIN  128
#define COUT 128
#define ODIM 1024
#define DDIM 4096
#define NCH  16

typedef short bf16x8 __attribute__((ext_vector_type(8)));
typedef short s16x4  __attribute__((ext_vector_type(4)));
typedef float f32x4  __attribute__((ext_vector_type(4)));

__device__ __forceinline__ void gld_lds16(const float* g, float* l) {
    __builtin_amdgcn_global_load_lds(
        (const __attribute__((address_space(1))) void*)g,
        (__attribute__((address_space(3))) void*)l, 16, 0, 0);
}
__device__ __forceinline__ unsigned cvtpk(float a, float b) {
    unsigned r;
    asm("v_cvt_pk_bf16_f32 %0, %1, %2" : "=v"(r) : "v"(a), "v"(b));
    return r;
}

__global__ __launch_bounds__(1024, 4)
void nolc_kernel(const float* __restrict__ xg,
                 const float* __restrict__ wg,
                 float* __restrict__ outg) {
    __shared__ float slab[3][8192];   // 3 x 32 KB ring: x_c -> slot (2c)%3, w_c -> (2c+1)%3
    __shared__ short tile[16384];     // 32 KB bf16: 128 rows (0-63 x=b, 64-127 w=o') x 128 shorts

    const int bid  = blockIdx.x;
    const int gidx = (bid & 7) * 64 + (bid >> 3);   // XCD-contiguous (512 % 8 == 0)
    const int ng   = gidx >> 1;                      // 0..255 (4 n each)
    const int oh   = gidx & 1;                       // o-half

    const int t    = threadIdx.x;
    const int lane = t & 63;
    const int wave = t >> 6;          // 0..15
    const int bt   = wave & 3;        // b 16-row tile
    const int ot   = wave >> 2;       // o 16-col tile
    const int r16  = lane & 15;
    const int kg   = lane >> 4;

    // ---- staging decode: unit u = (row, ii); lane covers piece n = lane&3 ----
    const int u0   = wave * 32 + (lane >> 2);   // j2=0 unit
    const int row0 = u0 >> 3;                   // 0..61 (j2=1: row0+2)
    const int ii0  = u0 & 7;
    const int sn   = lane & 3;

    const size_t xo0 = ((size_t)(row0 * CIN + ii0)) * DDIM + ng * 16 + sn * 4;
    const size_t xo1 = xo0 + (size_t)2 * CIN * DDIM;
    const size_t wo0 = ((size_t)((oh * 64 + row0) * CIN + ii0)) * DDIM + ng * 16 + sn * 4;
    const size_t wo1 = wo0 + (size_t)2 * CIN * DDIM;
    const int lbase  = wave * 512;              // float idx of this wave's region in a slot
    const int lpiece = lane * 4;                // my 16B piece within a region

    f32x4 acc[4];
#pragma unroll
    for (int n = 0; n < 4; ++n) acc[n] = (f32x4){0.f, 0.f, 0.f, 0.f};

    // prologue: x0 -> slot0, w0 -> slot1
    gld_lds16(xg + xo0, &slab[0][lbase]);
    gld_lds16(xg + xo1, &slab[0][lbase + 256]);
    gld_lds16(wg + wo0, &slab[1][lbase]);
    gld_lds16(wg + wo1, &slab[1][lbase + 256]);

#pragma unroll 1
    for (int c = 0; c < NCH; ++c) {
        const size_t co = (size_t)c * 8 * DDIM;
        const int sx  = (2 * c) % 3;
        const int sw  = (2 * c + 1) % 3;
        const int sx1 = (2 * c + 2) % 3;    // = w_{c-1}'s slot (freed last iter)
        const int sw1 = (2 * c + 3) % 3;    // = x_c's slot (freed at B_x below)

        // ---- issue x(c+1); retire x(c) (counted, w(c)+x(c+1) stay in flight) ----
        if (c + 1 < NCH) {
            const size_t cn = co + 8 * DDIM;
            gld_lds16(xg + xo0 + cn, &slab[sx1][lbase]);
            gld_lds16(xg + xo1 + cn, &slab[sx1][lbase + 256]);
            asm volatile("s_waitcnt vmcnt(4)" ::: "memory");
        } else {
            asm volatile("s_waitcnt vmcnt(2)" ::: "memory");
        }
        __builtin_amdgcn_sched_barrier(0);

        // ---- read back MY x pieces (linear, own region: no cross-wave dep) ----
        float4 fx0 = *reinterpret_cast<const float4*>(&slab[sx][lbase + lpiece]);
        float4 fx1 = *reinterpret_cast<const float4*>(&slab[sx][lbase + 256 + lpiece]);
        {   // cvt + swizzled tile write (x rows row0, row0+2)
            const int s5  = ii0 * 4 + sn;
            const int spA = (s5 & 16) | ((s5 ^ (row0 & 15)) & 15);
            const int spB = (s5 & 16) | ((s5 ^ ((row0 + 2) & 15)) & 15);
            uint2 pa, pb;
            pa.x = cvtpk(fx0.x, fx0.y); pa.y = cvtpk(fx0.z, fx0.w);
            pb.x = cvtpk(fx1.x, fx1.y); pb.y = cvtpk(fx1.z, fx1.w);
            *reinterpret_cast<uint2*>(&tile[row0 * 128 + spA * 4]) = pa;
            *reinterpret_cast<uint2*>(&tile[(row0 + 2) * 128 + spB * 4]) = pb;
        }
        asm volatile("s_waitcnt lgkmcnt(0)" ::: "memory");
        __builtin_amdgcn_sched_barrier(0);
        __builtin_amdgcn_s_barrier();   // B_x: all waves done reading x_c slab

        // ---- issue w(c+1) into x_c's slot; retire w(c) ----
        if (c + 1 < NCH) {
            const size_t cn = co + 8 * DDIM;
            gld_lds16(wg + wo0 + cn, &slab[sw1][lbase]);
            gld_lds16(wg + wo1 + cn, &slab[sw1][lbase + 256]);
            asm volatile("s_waitcnt vmcnt(4)" ::: "memory");
        } else {
            asm volatile("s_waitcnt vmcnt(0)" ::: "memory");
        }
        __builtin_amdgcn_sched_barrier(0);

        float4 fw0 = *reinterpret_cast<const float4*>(&slab[sw][lbase + lpiece]);
        float4 fw1 = *reinterpret_cast<const float4*>(&slab[sw][lbase + 256 + lpiece]);
        {   // cvt + tile write (w rows 64+row0, 64+row0+2)
            const int s5  = ii0 * 4 + sn;
            const int trA = 64 + row0, trB = 64 + row0 + 2;
            const int spA = (s5 & 16) | ((s5 ^ (trA & 15)) & 15);
            const int spB = (s5 & 16) | ((s5 ^ (trB & 15)) & 15);
            uint2 pa, pb;
            pa.x = cvtpk(fw0.x, fw0.y); pa.y = cvtpk(fw0.z, fw0.w);
            pb.x = cvtpk(fw1.x, fw1.y); pb.y = cvtpk(fw1.z, fw1.w);
            *reinterpret_cast<uint2*>(&tile[trA * 128 + spA * 4]) = pa;
            *reinterpret_cast<uint2*>(&tile[trB * 128 + spB * 4]) = pb;
        }
        asm volatile("s_waitcnt lgkmcnt(0)" ::: "memory");
        __builtin_amdgcn_sched_barrier(0);
        __builtin_amdgcn_s_barrier();   // B_tile: bf16 tile complete

        // ---- phase-B: 4 MFMA (K=32 = 8 i x 4 k), conflict-free swizzled reads ----
        const int rowA = bt * 16 + r16;        // &15 == r16
        const int rowB = 64 + ot * 16 + r16;   // &15 == r16
#pragma unroll
        for (int n = 0; n < 4; ++n) {
            const int sA0 = (kg * 2) * 4 + n, sA1 = (kg * 2 + 1) * 4 + n;
            const int pA0 = (sA0 & 16) | ((sA0 ^ r16) & 15);
            const int pA1 = (sA1 & 16) | ((sA1 ^ r16) & 15);
            s16x4 a0 = *reinterpret_cast<const s16x4*>(&tile[rowA * 128 + pA0 * 4]);
            s16x4 a1 = *reinterpret_cast<const s16x4*>(&tile[rowA * 128 + pA1 * 4]);
            s16x4 b0 = *reinterpret_cast<const s16x4*>(&tile[rowB * 128 + pA0 * 4]);
            s16x4 b1 = *reinterpret_cast<const s16x4*>(&tile[rowB * 128 + pA1 * 4]);
            bf16x8 A = __builtin_shufflevector(a0, a1, 0, 1, 2, 3, 4, 5, 6, 7);
            bf16x8 B = __builtin_shufflevector(b0, b1, 0, 1, 2, 3, 4, 5, 6, 7);
            acc[n] = __builtin_amdgcn_mfma_f32_16x16x32_bf16(A, B, acc[n], 0, 0, 0);
        }
        __builtin_amdgcn_s_barrier();   // B_done: tile + w-slab free for next iter
    }

    // ---- epilogue (verified mapping: col = o-local, row = kg*4+reg) ----
    const float scale = 0.08838834764831845f;  // 1/sqrt(128)
    const int o = oh * 64 + ot * 16 + r16;
#pragma unroll
    for (int r = 0; r < 4; ++r) {
        const int b = bt * 16 + kg * 4 + r;
        float4 v;
        v.x = acc[0][r] * scale;
        v.y = acc[1][r] * scale;
        v.z = acc[2][r] * scale;
        v.w = acc[3][r] * scale;
        *reinterpret_cast<float4*>(outg + ((size_t)b * COUT + o) * ODIM + ng * 4) = v;
    }
}

extern "C" void kernel_launch(void* const* d_in, const int* in_sizes, int n_in,
                              void* d_out, int out_size, void* d_ws, size_t ws_size,
                              hipStream_t stream) {
    const float* x = (const float*)d_in[0];
    const float* w = (const float*)d_in[1];
    float* out = (float*)d_out;
    nolc_kernel<<<dim3(512), dim3(1024), 0, stream>>>(x, w, out);
}